// Round 6
// baseline (687.218 us; speedup 1.0000x reference)
//
#include <hip/hip_runtime.h>
#include <hip/hip_bf16.h>

// PointerNetwork: B=4096, L=10, IN=8, H=512, W=512. fp32 in/out, ws=256MiB.
// log_softmax over size-1 axes => hi==he==0. Surviving compute:
//   enc GRU, ew3 = h_enc @ w3^T, dec GRU, a4 = h_dec @ w4^T,
//   out_seq = tanh(ew3+a4)@v2, out_ori = h_dec @ wori[:,H:2H]^T + bori.
// Round 12: gru_fused restructured: 128x64 tile (256 blocks x 512 thr,
// 1/CU), A-in-LDS dbuf (32KB) + B(weights)-in-REGISTERS dbuf (B has zero
// intra-block sharing -> LDS staging was pure overhead), counted vmcnt(8),
// XCD-patch block swizzle (4bx x 8by per XCD), fp32 h master REMOVED
// (blend from bf16 Aprev; bf16 chain error ~1e-3 << threshold).

#define B_   4096
#define L_   10
#define IN_  8
#define H_   512
#define H3_  1536
#define W_   512
#define ORI_BASE (B_ * L_ * L_)   // 409600

typedef __attribute__((ext_vector_type(8))) short s8v;
typedef __attribute__((ext_vector_type(4))) short s4v;
typedef __attribute__((ext_vector_type(4))) float f4v;

#define LOG2E  1.4426950408889634f
#define LOG2E2 2.8853900817779268f

__device__ __forceinline__ float sig_fast(float x) {
  float e = __builtin_amdgcn_exp2f(-x * LOG2E);
  return __builtin_amdgcn_rcpf(1.f + e);
}
__device__ __forceinline__ float tanh_fast(float x) {
  float e = __builtin_amdgcn_exp2f(x * LOG2E2);
  return 1.f - 2.f * __builtin_amdgcn_rcpf(e + 1.f);
}
__device__ __forceinline__ short f2bf(float f) {
  __hip_bfloat16 h = __float2bfloat16(f);
  return __builtin_bit_cast(short, h);
}
__device__ __forceinline__ float bf2f(short s) {
  __hip_bfloat16 h = __builtin_bit_cast(__hip_bfloat16, s);
  return __bfloat162float(h);
}
__device__ __forceinline__ void stc(float* p, float v) { *p = v; }
__device__ __forceinline__ void stc(short* p, float v) { *p = f2bf(v); }

// ---- fused prep: all fp32->bf16 conversions in one dispatch (6 segments) ----
__global__ __launch_bounds__(256) void prep_all(
    const float* __restrict__ s0, short* __restrict__ d0,   // enc_whh 786432
    const float* __restrict__ s1, short* __restrict__ d1,   // dec_whh 786432
    const float* __restrict__ s2, short* __restrict__ d2,   // dec_wih 786432
    const float* __restrict__ s3, short* __restrict__ d3,   // w3      262144
    const float* __restrict__ s4, short* __restrict__ d4,   // w4      262144
    const float* __restrict__ s5, short* __restrict__ d5)   // dec_in  2097152
{
  long i8 = (long)blockIdx.x * 256 + threadIdx.x;   // unit = 8 elements
  const float* s; short* d; long off;
  if      (i8 < 98304)  { s = s0; d = d0; off = i8; }
  else if (i8 < 196608) { s = s1; d = d1; off = i8 - 98304; }
  else if (i8 < 294912) { s = s2; d = d2; off = i8 - 196608; }
  else if (i8 < 327680) { s = s3; d = d3; off = i8 - 294912; }
  else if (i8 < 360448) { s = s4; d = d4; off = i8 - 327680; }
  else if (i8 < 622592) { s = s5; d = d5; off = i8 - 360448; }
  else return;
  const float* sp = s + off * 8;
  s8v v;
#pragma unroll
  for (int j = 0; j < 8; ++j) v[j] = f2bf(sp[j]);
  *(s8v*)(d + off * 8) = v;
}

// Fold embedding into encoder input weight. One wave per g-row (1536 waves).
__global__ __launch_bounds__(256) void build_wc(
    const float* __restrict__ enc_wih, const float* __restrict__ emb_w,
    const float* __restrict__ emb_b, const float* __restrict__ enc_bih,
    float* __restrict__ Wc, float* __restrict__ bc)
{
  __shared__ float se[H_ * IN_];   // 16 KB
  __shared__ float sb[H_];         // 2 KB
  const int tid = threadIdx.x;
  for (int i = tid; i < H_ * IN_; i += 256) se[i] = emb_w[i];
  for (int i = tid; i < H_; i += 256) sb[i] = emb_b[i];
  __syncthreads();
  int g = (blockIdx.x * 256 + tid) >> 6;
  int lane = tid & 63;
  const float* wr = enc_wih + (long)g * H_ + lane * 8;
  float w8[8];
#pragma unroll
  for (int j = 0; j < 8; ++j) w8[j] = wr[j];
  float acc[9] = {};
#pragma unroll
  for (int kk = 0; kk < 8; ++kk) {
    int k = lane * 8 + kk;
#pragma unroll
    for (int j = 0; j < 8; ++j) acc[j] += w8[kk] * se[k * IN_ + j];
    acc[8] += w8[kk] * sb[k];
  }
#pragma unroll
  for (int j = 0; j < 9; ++j)
#pragma unroll
    for (int off = 32; off; off >>= 1) acc[j] += __shfl_down(acc[j], off, 64);
  if (lane == 0) {
#pragma unroll
    for (int j = 0; j < 8; ++j) Wc[g * IN_ + j] = acc[j];
    bc[g] = acc[8] + enc_bih[g];
  }
}

// ---- Pipelined bf16 MFMA GEMM: C[M,N] = (A@B^T (+bias))*scale.
// 128x128 tile, BK=64, double-buffered LDS (64KB, 2 blk/CU), counted
// vmcnt(8), XOR-swizzled 16B chunks (both-sides), setprio around MFMA.
template <typename CT>
__global__ __launch_bounds__(256) void gemm_bf16(
    const short* __restrict__ A, long lda,
    const short* __restrict__ Bw, long ldb,
    const float* __restrict__ bias,
    CT* __restrict__ C, long ldc, int K, float scale)
{
  __shared__ short As[2][128 * 64];   // 32 KB
  __shared__ short Bs[2][128 * 64];   // 32 KB
  const int tid = threadIdx.x;
  const long row0 = (long)blockIdx.y * 128;
  const long col0 = (long)blockIdx.x * 128;
  const int wave = tid >> 6, lane = tid & 63;
  const int wm = (wave & 1) * 64, wn = (wave >> 1) * 64;
  const int r16 = lane & 15, quad = lane >> 4;
  const int sw = r16 & 7;
  f4v acc[4][4] = {};

  auto stage = [&](int buf, int k0) {
#pragma unroll
    for (int r = 0; r < 4; ++r) {             // A: 128x64 = 1024 chunks
      int idx = r * 256 + tid;
      int m = idx >> 3, c8 = idx & 7;
      int src = c8 ^ (m & 7);
      __builtin_amdgcn_global_load_lds(
          (const __attribute__((address_space(1))) void*)(A + (row0 + m) * lda + k0 + src * 8),
          (__attribute__((address_space(3))) void*)(&As[buf][idx * 8]), 16, 0, 0);
    }
#pragma unroll
    for (int r = 0; r < 4; ++r) {             // B: 128x64 = 1024 chunks
      int idx = r * 256 + tid;
      int m = idx >> 3, c8 = idx & 7;
      int src = c8 ^ (m & 7);
      __builtin_amdgcn_global_load_lds(
          (const __attribute__((address_space(1))) void*)(Bw + (col0 + m) * ldb + k0 + src * 8),
          (__attribute__((address_space(3))) void*)(&Bs[buf][idx * 8]), 16, 0, 0);
    }
  };

  const int nk = K >> 6;
  stage(0, 0);
  for (int k = 0; k < nk; ++k) {
    if (k < nk - 1) {
      stage((k + 1) & 1, (k + 1) * 64);
      asm volatile("s_waitcnt vmcnt(8)" ::: "memory");   // cur's 8 loads done
    } else {
      asm volatile("s_waitcnt vmcnt(0)" ::: "memory");
    }
    __builtin_amdgcn_s_barrier();
    const short* Asc = As[k & 1];
    const short* Bsc = Bs[k & 1];
    s8v af[4][2], bf[4][2];
#pragma unroll
    for (int i = 0; i < 4; ++i)
#pragma unroll
      for (int hh = 0; hh < 2; ++hh)
        af[i][hh] = *(const s8v*)&Asc[(wm + i * 16 + r16) * 64 + ((hh * 4 + quad) ^ sw) * 8];
#pragma unroll
    for (int j = 0; j < 4; ++j)
#pragma unroll
      for (int hh = 0; hh < 2; ++hh)
        bf[j][hh] = *(const s8v*)&Bsc[(wn + j * 16 + r16) * 64 + ((hh * 4 + quad) ^ sw) * 8];
    __builtin_amdgcn_s_setprio(1);
#pragma unroll
    for (int hh = 0; hh < 2; ++hh)
#pragma unroll
      for (int i = 0; i < 4; ++i)
#pragma unroll
        for (int j = 0; j < 4; ++j)
          acc[i][j] = __builtin_amdgcn_mfma_f32_16x16x32_bf16(af[i][hh], bf[j][hh], acc[i][j], 0, 0, 0);
    __builtin_amdgcn_s_setprio(0);
    __builtin_amdgcn_s_barrier();
  }

#pragma unroll
  for (int i = 0; i < 4; ++i) {
    long rbase = row0 + wm + i * 16 + quad * 4;
#pragma unroll
    for (int j = 0; j < 4; ++j) {
      long c = col0 + wn + j * 16 + r16;
      float bv = bias ? bias[c] : 0.f;
#pragma unroll
      for (int rg = 0; rg < 4; ++rg)
        stc(&C[(rbase + rg) * ldc + c], (acc[i][j][rg] + bv) * scale);
    }
  }
}

// ---- Fused GRU step, Round-12 structure.
// Tile 128 rows x 64 cols x 3 gates. Grid 256 flat (1 blk/CU), 512 thr
// (8 waves: rw=wv>>2 row-half, cw=wv&3 col-16). A (h_prev) in LDS dbuf
// 32KB, XOR-swizzled; B (weights) in REGISTER dbuf (6 global b128/iter);
// counted vmcnt(8) = A(k+1)x2 + B(k+1)x6. XCD-patch swizzle 4bx x 8by.
template <bool ENC>
__global__ __launch_bounds__(512) void gru_fused(
    const short* __restrict__ Aprev,  // (B,H) bf16 h_{t-1}
    const short* __restrict__ Whh,    // (3H,H) bf16
    const float* __restrict__ bhh,    // (3H)
    const short* __restrict__ xg,     // (B,3H) bf16 (decoder)
    const float* __restrict__ items_t,// encoder: &items[0][t][0], row stride 80
    const float* __restrict__ Wc,     // (3H,8)
    const float* __restrict__ bc,     // (3H)
    short* __restrict__ hout)         // (B,H) bf16 history slice
{
  __shared__ short As[2][128 * 64];   // 32 KB
  const int tid = threadIdx.x;
  const int f = blockIdx.x;
  // XCD-patch swizzle: assumes XCD = blockIdx % 8 round-robin (heuristic).
  // XCD x owns bx in [4*(x>>2), +4) x by in [8*(x&3), +8).
  const int x = f & 7, jj = f >> 3;
  const int bx = 4 * (x >> 2) + (jj & 3);
  const int by = 8 * (x & 3) + (jj >> 2);
  const long row0 = (long)by * 128;
  const int col0 = bx * 64;
  const int wv = tid >> 6, lane = tid & 63;
  const int rw = wv >> 2, cw = wv & 3;
  const int r16 = lane & 15, quad = lane >> 4;
  const int sw = r16 & 7;
  const int col = col0 + cw * 16 + r16;

  f4v acc[3][4] = {};   // [gate][frag-row]
  s8v bfr[2][3][2];     // register B double-buffer

  auto stageA = [&](int buf, int k0) {
#pragma unroll
    for (int r = 0; r < 2; ++r) {             // A: 128x64 = 1024 chunks
      int idx = r * 512 + tid;
      int m = idx >> 3, c8 = idx & 7;
      int src = c8 ^ (m & 7);
      __builtin_amdgcn_global_load_lds(
          (const __attribute__((address_space(1))) void*)(Aprev + (row0 + m) * H_ + k0 + src * 8),
          (__attribute__((address_space(3))) void*)(&As[buf][idx * 8]), 16, 0, 0);
    }
  };
  // per-lane weight base: row (g*512+col), k-offset quad*8
  const short* wp0 = Whh + ((long)(0 * H_ + col)) * H_ + quad * 8;
  const short* wp1 = Whh + ((long)(1 * H_ + col)) * H_ + quad * 8;
  const short* wp2 = Whh + ((long)(2 * H_ + col)) * H_ + quad * 8;
  auto loadB = [&](int buf, int k0) {
#pragma unroll
    for (int hh = 0; hh < 2; ++hh) {
      bfr[buf][0][hh] = *(const s8v*)(wp0 + k0 + hh * 32);
      bfr[buf][1][hh] = *(const s8v*)(wp1 + k0 + hh * 32);
      bfr[buf][2][hh] = *(const s8v*)(wp2 + k0 + hh * 32);
    }
  };

  stageA(0, 0);
  loadB(0, 0);
#pragma unroll
  for (int k = 0; k < 8; ++k) {
    if (k < 7) {
      stageA((k + 1) & 1, (k + 1) * 64);
      loadB((k + 1) & 1, (k + 1) * 64);
      asm volatile("s_waitcnt vmcnt(8)" ::: "memory");   // A(k) complete
    } else {
      asm volatile("s_waitcnt vmcnt(0)" ::: "memory");
    }
    __builtin_amdgcn_s_barrier();
    s8v af[4][2];
#pragma unroll
    for (int i = 0; i < 4; ++i)
#pragma unroll
      for (int hh = 0; hh < 2; ++hh)
        af[i][hh] = *(const s8v*)&As[k & 1][(rw * 64 + i * 16 + r16) * 64 + ((hh * 4 + quad) ^ sw) * 8];
    __builtin_amdgcn_s_setprio(1);
#pragma unroll
    for (int hh = 0; hh < 2; ++hh)
#pragma unroll
      for (int g = 0; g < 3; ++g)
#pragma unroll
        for (int i = 0; i < 4; ++i)
          acc[g][i] = __builtin_amdgcn_mfma_f32_16x16x32_bf16(af[i][hh], bfr[k & 1][g][hh], acc[g][i], 0, 0, 0);
    __builtin_amdgcn_s_setprio(0);
    __builtin_amdgcn_s_barrier();
  }

  // Column owned by this thread (C/D layout: col=lane&15, row=quad*4+reg).
  float wc[3][8], bcv[3];
  if (ENC) {
#pragma unroll
    for (int g = 0; g < 3; ++g) {
      const float* wr = Wc + ((long)g * H_ + col) * IN_;
#pragma unroll
      for (int j = 0; j < 8; ++j) wc[g][j] = wr[j];
      bcv[g] = bc[g * H_ + col];
    }
    // stage items rows into LDS (reuse As): 128 rows x 8 fp32 = 1024 f32
    float* itemS = (float*)As;
    int i2 = tid * 2;
    int m = i2 >> 3, j = i2 & 7;
    itemS[i2] = items_t[(row0 + m) * (L_ * IN_) + j];
    itemS[i2 + 1] = items_t[(row0 + m) * (L_ * IN_) + j + 1];
    __syncthreads();
  }
  float bhr = bhh[col], bhz = bhh[col + H_], bhn = bhh[col + 2 * H_];

#pragma unroll
  for (int i = 0; i < 4; ++i) {
#pragma unroll
    for (int rg = 0; rg < 4; ++rg) {
      int rl = rw * 64 + i * 16 + quad * 4 + rg;
      long row = row0 + rl;
      float xr, xz, xn;
      if (ENC) {
        const float* it = (const float*)As + rl * 8;
        xr = bcv[0]; xz = bcv[1]; xn = bcv[2];
#pragma unroll
        for (int j = 0; j < 8; ++j) {
          float iv = it[j];
          xr += iv * wc[0][j];
          xz += iv * wc[1][j];
          xn += iv * wc[2][j];
        }
      } else {
        long gx = row * H3_ + col;
        xr = bf2f(xg[gx]); xz = bf2f(xg[gx + H_]); xn = bf2f(xg[gx + 2 * H_]);
      }
      float r = sig_fast(xr + acc[0][i][rg] + bhr);
      float z = sig_fast(xz + acc[1][i][rg] + bhz);
      float n = tanh_fast(xn + r * (acc[2][i][rg] + bhn));
      long hi = row * H_ + col;
      float hp = bf2f(Aprev[hi]);                 // bf16 h_{t-1} (L2-hot)
      float hv = (1.f - z) * n + z * hp;
      hout[hi] = f2bf(hv);
    }
  }
}

// ---- batched out_seq: one block per b. ew3/a4 arrive pre-scaled by LOG2E2,
// staged as f32 in LDS with conflict-free contiguous-quarter access.
// tanh(x) = 1 - 2*rcp(exp2(x*LOG2E2)+1); "1" folded into svtot=sum(v2).
__global__ __launch_bounds__(256) void out_seq_all(
    const short* __restrict__ ew3,   // (Lenc, B, W) bf16, prescaled
    const short* __restrict__ a4,    // (Ldec, B, W) bf16, prescaled
    const float* __restrict__ v2,
    float* __restrict__ out)
{
  __shared__ float se[L_ * W_];   // 20 KB
  __shared__ float sa[L_ * W_];   // 20 KB
  const int b = blockIdx.x;
  const int tid = threadIdx.x;
  for (int i = tid; i < L_ * 128; i += 256) {
    int row = i >> 7, q = i & 127;
    s4v ev = *(const s4v*)(ew3 + ((long)row * B_ + b) * W_ + q * 4);
    s4v av = *(const s4v*)(a4 + ((long)row * B_ + b) * W_ + q * 4);
    f4v e, a;
#pragma unroll
    for (int j = 0; j < 4; ++j) { e[j] = bf2f(ev[j]); a[j] = bf2f(av[j]); }
    *(f4v*)(se + row * W_ + q * 4) = e;
    *(f4v*)(sa + row * W_ + q * 4) = a;
  }
  const int wave = tid >> 6, lane = tid & 63;
  float sv0[4], sv1[4], svtot = 0.f;
#pragma unroll
  for (int q = 0; q < 4; ++q) {
    float v = v2[lane * 4 + q];
    sv0[q] = -2.f * v; svtot += v;
    v = v2[256 + lane * 4 + q];
    sv1[q] = -2.f * v; svtot += v;
  }
#pragma unroll
  for (int off = 32; off; off >>= 1) svtot += __shfl_down(svtot, off, 64);
  svtot = __shfl(svtot, 0, 64);
  __syncthreads();

  int tprev = -1;
  f4v a0, a1;
#pragma unroll
  for (int pp = 0; pp < 25; ++pp) {
    int p = wave * 25 + pp;       // 100 (t,l) pairs over 4 waves
    int t = p / L_, l = p - t * L_;
    if (t != tprev) {             // wave-uniform branch; a-regs reused
      a0 = *(const f4v*)(sa + t * W_ + lane * 4);
      a1 = *(const f4v*)(sa + t * W_ + 256 + lane * 4);
      tprev = t;
    }
    f4v e0 = *(const f4v*)(se + l * W_ + lane * 4);
    f4v e1 = *(const f4v*)(se + l * W_ + 256 + lane * 4);
    float acc = 0.f;
#pragma unroll
    for (int q = 0; q < 4; ++q) {
      float x0 = __builtin_amdgcn_exp2f(e0[q] + a0[q]);
      acc += sv0[q] * __builtin_amdgcn_rcpf(x0 + 1.f);
      float x1 = __builtin_amdgcn_exp2f(e1[q] + a1[q]);
      acc += sv1[q] * __builtin_amdgcn_rcpf(x1 + 1.f);
    }
#pragma unroll
    for (int off = 32; off; off >>= 1) acc += __shfl_down(acc, off, 64);
    if (lane == 0) out[((long)b * L_ + t) * L_ + l] = svtot + acc;
  }
}

// ---- batched out_ori: one wave per (b,t). ----
__global__ __launch_bounds__(256) void out_ori_all(
    const short* __restrict__ dh,    // (Ldec, B, H) bf16
    const float* __restrict__ wori, const float* __restrict__ bori,
    float* __restrict__ out)
{
  int wid = (blockIdx.x * 256 + threadIdx.x) >> 6;   // b*L + t
  int lane = threadIdx.x & 63;
  int b = wid / L_, t = wid - b * L_;
  s8v hv = *(const s8v*)(dh + ((long)t * B_ + b) * H_ + lane * 8);
  float hf[8];
#pragma unroll
  for (int j = 0; j < 8; ++j) hf[j] = bf2f(hv[j]);
  float res[6];
#pragma unroll
  for (int o = 0; o < 6; ++o) {
    const float* wr = wori + (long)o * H3_ + H_ + lane * 8;
    float acc = 0.f;
#pragma unroll
    for (int j = 0; j < 8; ++j) acc += hf[j] * wr[j];
#pragma unroll
    for (int off = 32; off; off >>= 1) acc += __shfl_down(acc, off, 64);
    res[o] = acc;
  }
  if (lane == 0) {
    float* po = out + ORI_BASE + ((long)b * L_ + t) * 6;
#pragma unroll
    for (int o = 0; o < 6; ++o) po[o] = res[o] + bori[o];
  }
}

extern "C" void kernel_launch(void* const* d_in, const int* in_sizes, int n_in,
                              void* d_out, int out_size, void* d_ws, size_t ws_size,
                              hipStream_t stream)
{
  const float* items   = (const float*)d_in[0];
  const float* dec_in  = (const float*)d_in[1];
  const float* emb_w   = (const float*)d_in[2];
  const float* emb_b   = (const float*)d_in[3];
  const float* enc_wih = (const float*)d_in[4];
  const float* enc_whh = (const float*)d_in[5];
  const float* enc_bih = (const float*)d_in[6];
  const float* enc_bhh = (const float*)d_in[7];
  const float* dec_wih = (const float*)d_in[8];
  const float* dec_whh = (const float*)d_in[9];
  const float* dec_bih = (const float*)d_in[10];
  const float* dec_bhh = (const float*)d_in[11];
  const float* w3      = (const float*)d_in[14];
  const float* w4      = (const float*)d_in[15];
  const float* v2      = (const float*)d_in[20];
  const float* wori    = (const float*)d_in[23];
  const float* bori    = (const float*)d_in[24];
  float* out = (float*)d_out;

  char* ws = (char*)d_ws;
  size_t off = 0;
  auto alloc = [&](size_t bytes) { size_t o = off; off += (bytes + 255) & ~255UL; return o; };
  float* Wc       = (float*)(ws + alloc(H3_ * IN_ * 4));
  float* bc       = (float*)(ws + alloc(H3_ * 4));
  short* xgb      = (short*)(ws + alloc((size_t)B_ * H3_ * 2));          // 12 MiB
  short* enc_hist = (short*)(ws + alloc((size_t)11 * B_ * H_ * 2));      // 44 MiB
  short* dec_hist = (short*)(ws + alloc((size_t)L_ * B_ * H_ * 2));      // 40 MiB
  short* ew3      = (short*)(ws + alloc((size_t)L_ * B_ * W_ * 2));      // 40 MiB
  short* a4       = (short*)(ws + alloc((size_t)L_ * B_ * W_ * 2));      // 40 MiB
  short* whh_e    = (short*)(ws + alloc((size_t)H3_ * H_ * 2));
  short* whh_d    = (short*)(ws + alloc((size_t)H3_ * H_ * 2));
  short* wih_d    = (short*)(ws + alloc((size_t)H3_ * H_ * 2));
  short* w3b      = (short*)(ws + alloc((size_t)W_ * H_ * 2));
  short* w4b      = (short*)(ws + alloc((size_t)W_ * H_ * 2));
  short* decb     = (short*)(ws + alloc((size_t)B_ * H_ * 2));           // 4 MiB

  // ---- prep (one fused conversion dispatch) ----
  prep_all<<<(622592 + 255) / 256, 256, 0, stream>>>(
      enc_whh, whh_e, dec_whh, whh_d, dec_wih, wih_d,
      w3, w3b, w4, w4b, dec_in, decb);
  build_wc<<<384, 256, 0, stream>>>(enc_wih, emb_w, emb_b, enc_bih, Wc, bc);

  hipMemsetAsync(enc_hist, 0, (size_t)B_ * H_ * 2, stream);      // slice 0 = 0

  // xg_dec = dec_in @ dec_wih^T + dec_bih (fixed across decoder steps), bf16
  gemm_bf16<short><<<dim3(12, 32), 256, 0, stream>>>(
      decb, H_, wih_d, H_, dec_bih, xgb, H3_, H_, 1.f);

  // ---- Encoder recurrence: single fused kernel per step (xg inline) ----
  for (int t = 0; t < L_; ++t) {
    gru_fused<true><<<256, 512, 0, stream>>>(
        enc_hist + (size_t)t * B_ * H_, whh_e, enc_bhh, nullptr,
        items + (size_t)t * IN_, Wc, bc,
        enc_hist + (size_t)(t + 1) * B_ * H_);
  }

  // ---- Decoder recurrence ----
  for (int t = 0; t < L_; ++t) {
    const short* prev = (t == 0) ? enc_hist + (size_t)10 * B_ * H_
                                 : dec_hist + (size_t)(t - 1) * B_ * H_;
    gru_fused<false><<<256, 512, 0, stream>>>(
        prev, whh_d, dec_bhh, xgb, nullptr, nullptr, nullptr,
        dec_hist + (size_t)t * B_ * H_);
  }

  // ---- Batched epilogue (ew3/a4 prescaled by LOG2E2 for out_seq) ----
  gemm_bf16<short><<<dim3(4, 320), 256, 0, stream>>>(
      enc_hist + (size_t)B_ * H_, H_, w3b, H_, nullptr, ew3, W_, H_, LOG2E2);
  gemm_bf16<short><<<dim3(4, 320), 256, 0, stream>>>(
      dec_hist, H_, w4b, H_, nullptr, a4, W_, H_, LOG2E2);
  out_seq_all<<<B_, 256, 0, stream>>>(ew3, a4, v2, out);
  out_ori_all<<<(B_ * L_) / 4, 256, 0, stream>>>(dec_hist, wori, bori, out);
}

// Round 7
// 655.078 us; speedup vs baseline: 1.0491x; 1.0491x over previous
//
#include <hip/hip_runtime.h>
#include <hip/hip_bf16.h>

// PointerNetwork: B=4096, L=10, IN=8, H=512, W=512. fp32 in/out, ws=256MiB.
// log_softmax over size-1 axes => hi==he==0. Surviving compute:
//   enc GRU, ew3 = h_enc @ w3^T, dec GRU, a4 = h_dec @ w4^T,
//   out_seq = tanh(ew3+a4)@v2, out_ori = h_dec @ wori[:,H:2H]^T + bori.
// Round 13 = R5 skeleton + two isolated wins:
//  (a) gru_fused: B(weights) in REGISTER dbuf (zero intra-block sharing ->
//      LDS staging was overhead); LDS = A dbuf only (16KB) -> ~3-4 blk/CU
//      overlap (R6's failure was 512-thr 1 blk/CU lockstep, not B-in-regs);
//      fp32 h master removed (bf16 blend validated in R6, absmax unchanged).
//  (b) ew3/a4 epilogue GEMMs merged into one dispatch (blockIdx.z).

#define B_   4096
#define L_   10
#define IN_  8
#define H_   512
#define H3_  1536
#define W_   512
#define ORI_BASE (B_ * L_ * L_)   // 409600

typedef __attribute__((ext_vector_type(8))) short s8v;
typedef __attribute__((ext_vector_type(4))) short s4v;
typedef __attribute__((ext_vector_type(4))) float f4v;

#define LOG2E  1.4426950408889634f
#define LOG2E2 2.8853900817779268f

__device__ __forceinline__ float sig_fast(float x) {
  float e = __builtin_amdgcn_exp2f(-x * LOG2E);
  return __builtin_amdgcn_rcpf(1.f + e);
}
__device__ __forceinline__ float tanh_fast(float x) {
  float e = __builtin_amdgcn_exp2f(x * LOG2E2);
  return 1.f - 2.f * __builtin_amdgcn_rcpf(e + 1.f);
}
__device__ __forceinline__ short f2bf(float f) {
  __hip_bfloat16 h = __float2bfloat16(f);
  return __builtin_bit_cast(short, h);
}
__device__ __forceinline__ float bf2f(short s) {
  __hip_bfloat16 h = __builtin_bit_cast(__hip_bfloat16, s);
  return __bfloat162float(h);
}
__device__ __forceinline__ void stc(float* p, float v) { *p = v; }
__device__ __forceinline__ void stc(short* p, float v) { *p = f2bf(v); }

// ---- fused prep: all fp32->bf16 conversions in one dispatch (6 segments) ----
__global__ __launch_bounds__(256) void prep_all(
    const float* __restrict__ s0, short* __restrict__ d0,   // enc_whh 786432
    const float* __restrict__ s1, short* __restrict__ d1,   // dec_whh 786432
    const float* __restrict__ s2, short* __restrict__ d2,   // dec_wih 786432
    const float* __restrict__ s3, short* __restrict__ d3,   // w3      262144
    const float* __restrict__ s4, short* __restrict__ d4,   // w4      262144
    const float* __restrict__ s5, short* __restrict__ d5)   // dec_in  2097152
{
  long i8 = (long)blockIdx.x * 256 + threadIdx.x;   // unit = 8 elements
  const float* s; short* d; long off;
  if      (i8 < 98304)  { s = s0; d = d0; off = i8; }
  else if (i8 < 196608) { s = s1; d = d1; off = i8 - 98304; }
  else if (i8 < 294912) { s = s2; d = d2; off = i8 - 196608; }
  else if (i8 < 327680) { s = s3; d = d3; off = i8 - 294912; }
  else if (i8 < 360448) { s = s4; d = d4; off = i8 - 327680; }
  else if (i8 < 622592) { s = s5; d = d5; off = i8 - 360448; }
  else return;
  const float* sp = s + off * 8;
  s8v v;
#pragma unroll
  for (int j = 0; j < 8; ++j) v[j] = f2bf(sp[j]);
  *(s8v*)(d + off * 8) = v;
}

// Fold embedding into encoder input weight. One wave per g-row (1536 waves).
__global__ __launch_bounds__(256) void build_wc(
    const float* __restrict__ enc_wih, const float* __restrict__ emb_w,
    const float* __restrict__ emb_b, const float* __restrict__ enc_bih,
    float* __restrict__ Wc, float* __restrict__ bc)
{
  __shared__ float se[H_ * IN_];   // 16 KB
  __shared__ float sb[H_];         // 2 KB
  const int tid = threadIdx.x;
  for (int i = tid; i < H_ * IN_; i += 256) se[i] = emb_w[i];
  for (int i = tid; i < H_; i += 256) sb[i] = emb_b[i];
  __syncthreads();
  int g = (blockIdx.x * 256 + tid) >> 6;
  int lane = tid & 63;
  const float* wr = enc_wih + (long)g * H_ + lane * 8;
  float w8[8];
#pragma unroll
  for (int j = 0; j < 8; ++j) w8[j] = wr[j];
  float acc[9] = {};
#pragma unroll
  for (int kk = 0; kk < 8; ++kk) {
    int k = lane * 8 + kk;
#pragma unroll
    for (int j = 0; j < 8; ++j) acc[j] += w8[kk] * se[k * IN_ + j];
    acc[8] += w8[kk] * sb[k];
  }
#pragma unroll
  for (int j = 0; j < 9; ++j)
#pragma unroll
    for (int off = 32; off; off >>= 1) acc[j] += __shfl_down(acc[j], off, 64);
  if (lane == 0) {
#pragma unroll
    for (int j = 0; j < 8; ++j) Wc[g * IN_ + j] = acc[j];
    bc[g] = acc[8] + enc_bih[g];
  }
}

// ---- Pipelined bf16 MFMA GEMM: C[M,N] = (A@B^T (+bias))*scale.
// 128x128 tile, BK=64, double-buffered LDS (64KB, 2 blk/CU), counted
// vmcnt(8), XOR-swizzled 16B chunks (both-sides), setprio around MFMA.
template <typename CT>
__global__ __launch_bounds__(256) void gemm_bf16(
    const short* __restrict__ A, long lda,
    const short* __restrict__ Bw, long ldb,
    const float* __restrict__ bias,
    CT* __restrict__ C, long ldc, int K, float scale)
{
  __shared__ short As[2][128 * 64];   // 32 KB
  __shared__ short Bs[2][128 * 64];   // 32 KB
  const int tid = threadIdx.x;
  const long row0 = (long)blockIdx.y * 128;
  const long col0 = (long)blockIdx.x * 128;
  const int wave = tid >> 6, lane = tid & 63;
  const int wm = (wave & 1) * 64, wn = (wave >> 1) * 64;
  const int r16 = lane & 15, quad = lane >> 4;
  const int sw = r16 & 7;
  f4v acc[4][4] = {};

  auto stage = [&](int buf, int k0) {
#pragma unroll
    for (int r = 0; r < 4; ++r) {             // A: 128x64 = 1024 chunks
      int idx = r * 256 + tid;
      int m = idx >> 3, c8 = idx & 7;
      int src = c8 ^ (m & 7);
      __builtin_amdgcn_global_load_lds(
          (const __attribute__((address_space(1))) void*)(A + (row0 + m) * lda + k0 + src * 8),
          (__attribute__((address_space(3))) void*)(&As[buf][idx * 8]), 16, 0, 0);
    }
#pragma unroll
    for (int r = 0; r < 4; ++r) {             // B: 128x64 = 1024 chunks
      int idx = r * 256 + tid;
      int m = idx >> 3, c8 = idx & 7;
      int src = c8 ^ (m & 7);
      __builtin_amdgcn_global_load_lds(
          (const __attribute__((address_space(1))) void*)(Bw + (col0 + m) * ldb + k0 + src * 8),
          (__attribute__((address_space(3))) void*)(&Bs[buf][idx * 8]), 16, 0, 0);
    }
  };

  const int nk = K >> 6;
  stage(0, 0);
  for (int k = 0; k < nk; ++k) {
    if (k < nk - 1) {
      stage((k + 1) & 1, (k + 1) * 64);
      asm volatile("s_waitcnt vmcnt(8)" ::: "memory");   // cur's 8 loads done
    } else {
      asm volatile("s_waitcnt vmcnt(0)" ::: "memory");
    }
    __builtin_amdgcn_s_barrier();
    const short* Asc = As[k & 1];
    const short* Bsc = Bs[k & 1];
    s8v af[4][2], bf[4][2];
#pragma unroll
    for (int i = 0; i < 4; ++i)
#pragma unroll
      for (int hh = 0; hh < 2; ++hh)
        af[i][hh] = *(const s8v*)&Asc[(wm + i * 16 + r16) * 64 + ((hh * 4 + quad) ^ sw) * 8];
#pragma unroll
    for (int j = 0; j < 4; ++j)
#pragma unroll
      for (int hh = 0; hh < 2; ++hh)
        bf[j][hh] = *(const s8v*)&Bsc[(wn + j * 16 + r16) * 64 + ((hh * 4 + quad) ^ sw) * 8];
    __builtin_amdgcn_s_setprio(1);
#pragma unroll
    for (int hh = 0; hh < 2; ++hh)
#pragma unroll
      for (int i = 0; i < 4; ++i)
#pragma unroll
        for (int j = 0; j < 4; ++j)
          acc[i][j] = __builtin_amdgcn_mfma_f32_16x16x32_bf16(af[i][hh], bf[j][hh], acc[i][j], 0, 0, 0);
    __builtin_amdgcn_s_setprio(0);
    __builtin_amdgcn_s_barrier();
  }

#pragma unroll
  for (int i = 0; i < 4; ++i) {
    long rbase = row0 + wm + i * 16 + quad * 4;
#pragma unroll
    for (int j = 0; j < 4; ++j) {
      long c = col0 + wn + j * 16 + r16;
      float bv = bias ? bias[c] : 0.f;
#pragma unroll
      for (int rg = 0; rg < 4; ++rg)
        stc(&C[(rbase + rg) * ldc + c], (acc[i][j][rg] + bv) * scale);
    }
  }
}

// ---- Merged epilogue GEMM: z=0 -> ew3 = enc_hist@w3^T; z=1 -> a4 =
// dec_hist@w4^T. Same pipelined body, output *LOG2E2 as bf16.
__global__ __launch_bounds__(256) void gemm_epi(
    const short* __restrict__ Ae, const short* __restrict__ Ad,
    const short* __restrict__ w3b, const short* __restrict__ w4b,
    short* __restrict__ Ce, short* __restrict__ Cd)
{
  const short* A  = blockIdx.z ? Ad : Ae;
  const short* Bw = blockIdx.z ? w4b : w3b;
  short* C        = blockIdx.z ? Cd : Ce;
  __shared__ short As[2][128 * 64];
  __shared__ short Bs[2][128 * 64];
  const int tid = threadIdx.x;
  const long row0 = (long)blockIdx.y * 128;
  const long col0 = (long)blockIdx.x * 128;
  const int wave = tid >> 6, lane = tid & 63;
  const int wm = (wave & 1) * 64, wn = (wave >> 1) * 64;
  const int r16 = lane & 15, quad = lane >> 4;
  const int sw = r16 & 7;
  f4v acc[4][4] = {};

  auto stage = [&](int buf, int k0) {
#pragma unroll
    for (int r = 0; r < 4; ++r) {
      int idx = r * 256 + tid;
      int m = idx >> 3, c8 = idx & 7;
      int src = c8 ^ (m & 7);
      __builtin_amdgcn_global_load_lds(
          (const __attribute__((address_space(1))) void*)(A + (row0 + m) * H_ + k0 + src * 8),
          (__attribute__((address_space(3))) void*)(&As[buf][idx * 8]), 16, 0, 0);
    }
#pragma unroll
    for (int r = 0; r < 4; ++r) {
      int idx = r * 256 + tid;
      int m = idx >> 3, c8 = idx & 7;
      int src = c8 ^ (m & 7);
      __builtin_amdgcn_global_load_lds(
          (const __attribute__((address_space(1))) void*)(Bw + (col0 + m) * H_ + k0 + src * 8),
          (__attribute__((address_space(3))) void*)(&Bs[buf][idx * 8]), 16, 0, 0);
    }
  };

  stage(0, 0);
  for (int k = 0; k < 8; ++k) {
    if (k < 7) {
      stage((k + 1) & 1, (k + 1) * 64);
      asm volatile("s_waitcnt vmcnt(8)" ::: "memory");
    } else {
      asm volatile("s_waitcnt vmcnt(0)" ::: "memory");
    }
    __builtin_amdgcn_s_barrier();
    const short* Asc = As[k & 1];
    const short* Bsc = Bs[k & 1];
    s8v af[4][2], bf[4][2];
#pragma unroll
    for (int i = 0; i < 4; ++i)
#pragma unroll
      for (int hh = 0; hh < 2; ++hh)
        af[i][hh] = *(const s8v*)&Asc[(wm + i * 16 + r16) * 64 + ((hh * 4 + quad) ^ sw) * 8];
#pragma unroll
    for (int j = 0; j < 4; ++j)
#pragma unroll
      for (int hh = 0; hh < 2; ++hh)
        bf[j][hh] = *(const s8v*)&Bsc[(wn + j * 16 + r16) * 64 + ((hh * 4 + quad) ^ sw) * 8];
    __builtin_amdgcn_s_setprio(1);
#pragma unroll
    for (int hh = 0; hh < 2; ++hh)
#pragma unroll
      for (int i = 0; i < 4; ++i)
#pragma unroll
        for (int j = 0; j < 4; ++j)
          acc[i][j] = __builtin_amdgcn_mfma_f32_16x16x32_bf16(af[i][hh], bf[j][hh], acc[i][j], 0, 0, 0);
    __builtin_amdgcn_s_setprio(0);
    __builtin_amdgcn_s_barrier();
  }

#pragma unroll
  for (int i = 0; i < 4; ++i) {
    long rbase = row0 + wm + i * 16 + quad * 4;
#pragma unroll
    for (int j = 0; j < 4; ++j) {
      long c = col0 + wn + j * 16 + r16;
#pragma unroll
      for (int rg = 0; rg < 4; ++rg)
        C[(rbase + rg) * W_ + c] = f2bf(acc[i][j][rg] * LOG2E2);
    }
  }
}

// ---- Fused GRU step. Tile 64 rows x 64 cols x 3 gates. Grid (8,64) = 512
// blocks, 256 thr (4 waves). A (h_prev) in LDS dbuf 16KB (shared by all
// waves), XOR-swizzled; B (weights) in REGISTER dbuf (zero intra-block
// sharing). Counted vmcnt(8) = A(k+1)x2 + B(k+1)x6. No fp32 h master:
// blend from bf16 Aprev (validated R6).
template <bool ENC>
__global__ __launch_bounds__(256) void gru_fused(
    const short* __restrict__ Aprev,  // (B,H) bf16 h_{t-1}
    const short* __restrict__ Whh,    // (3H,H) bf16
    const float* __restrict__ bhh,    // (3H)
    const short* __restrict__ xg,     // (B,3H) bf16 (decoder)
    const float* __restrict__ items_t,// encoder: &items[0][t][0], row stride 80
    const float* __restrict__ Wc,     // (3H,8)
    const float* __restrict__ bc,     // (3H)
    short* __restrict__ hout)         // (B,H) bf16 history slice
{
  __shared__ short As[2][64 * 64];    // 16 KB total
  const int tid = threadIdx.x;
  const long row0 = (long)blockIdx.y * 64;
  const int col0 = blockIdx.x * 64;
  const int wave = tid >> 6, lane = tid & 63;
  const int r16 = lane & 15, quad = lane >> 4;
  const int sw = r16 & 7;
  const int col = col0 + wave * 16 + r16;

  f4v acc[3][4] = {};   // [gate][frag-row]
  s8v bfr[2][3][2];     // register B double-buffer

  auto stageA = [&](int buf, int k0) {
#pragma unroll
    for (int r = 0; r < 2; ++r) {             // A: 64x64 = 512 chunks
      int idx = r * 256 + tid;
      int m = idx >> 3, c8 = idx & 7;
      int src = c8 ^ (m & 7);
      __builtin_amdgcn_global_load_lds(
          (const __attribute__((address_space(1))) void*)(Aprev + (row0 + m) * H_ + k0 + src * 8),
          (__attribute__((address_space(3))) void*)(&As[buf][idx * 8]), 16, 0, 0);
    }
  };
  const short* wp0 = Whh + ((long)(0 * H_ + col)) * H_ + quad * 8;
  const short* wp1 = Whh + ((long)(1 * H_ + col)) * H_ + quad * 8;
  const short* wp2 = Whh + ((long)(2 * H_ + col)) * H_ + quad * 8;
  auto loadB = [&](int buf, int k0) {
#pragma unroll
    for (int hh = 0; hh < 2; ++hh) {
      bfr[buf][0][hh] = *(const s8v*)(wp0 + k0 + hh * 32);
      bfr[buf][1][hh] = *(const s8v*)(wp1 + k0 + hh * 32);
      bfr[buf][2][hh] = *(const s8v*)(wp2 + k0 + hh * 32);
    }
  };

  stageA(0, 0);
  loadB(0, 0);
#pragma unroll
  for (int k = 0; k < 8; ++k) {
    if (k < 7) {
      stageA((k + 1) & 1, (k + 1) * 64);
      loadB((k + 1) & 1, (k + 1) * 64);
      asm volatile("s_waitcnt vmcnt(8)" ::: "memory");   // iter-k loads done
    } else {
      asm volatile("s_waitcnt vmcnt(0)" ::: "memory");
    }
    __builtin_amdgcn_s_barrier();
    s8v af[4][2];
#pragma unroll
    for (int i = 0; i < 4; ++i)
#pragma unroll
      for (int hh = 0; hh < 2; ++hh)
        af[i][hh] = *(const s8v*)&As[k & 1][(i * 16 + r16) * 64 + ((hh * 4 + quad) ^ sw) * 8];
    __builtin_amdgcn_s_setprio(1);
#pragma unroll
    for (int hh = 0; hh < 2; ++hh)
#pragma unroll
      for (int g = 0; g < 3; ++g)
#pragma unroll
        for (int i = 0; i < 4; ++i)
          acc[g][i] = __builtin_amdgcn_mfma_f32_16x16x32_bf16(af[i][hh], bfr[k & 1][g][hh], acc[g][i], 0, 0, 0);
    __builtin_amdgcn_s_setprio(0);
    __builtin_amdgcn_s_barrier();
  }

  // Column owned by this thread (C/D layout: col=lane&15, row=quad*4+reg).
  float wc[3][8], bcv[3];
  if (ENC) {
#pragma unroll
    for (int g = 0; g < 3; ++g) {
      const float* wr = Wc + ((long)g * H_ + col) * IN_;
#pragma unroll
      for (int j = 0; j < 8; ++j) wc[g][j] = wr[j];
      bcv[g] = bc[g * H_ + col];
    }
    // stage items rows into LDS (reuse As): 64 rows x 8 fp32
    float* itemS = (float*)As;
    int i2 = tid * 2;
    int m = i2 >> 3, j = i2 & 7;
    itemS[i2] = items_t[(row0 + m) * (L_ * IN_) + j];
    itemS[i2 + 1] = items_t[(row0 + m) * (L_ * IN_) + j + 1];
    __syncthreads();
  }
  float bhr = bhh[col], bhz = bhh[col + H_], bhn = bhh[col + 2 * H_];

#pragma unroll
  for (int i = 0; i < 4; ++i) {
#pragma unroll
    for (int rg = 0; rg < 4; ++rg) {
      int rl = i * 16 + quad * 4 + rg;
      long row = row0 + rl;
      float xr, xz, xn;
      if (ENC) {
        const float* it = (const float*)As + rl * 8;
        xr = bcv[0]; xz = bcv[1]; xn = bcv[2];
#pragma unroll
        for (int j = 0; j < 8; ++j) {
          float iv = it[j];
          xr += iv * wc[0][j];
          xz += iv * wc[1][j];
          xn += iv * wc[2][j];
        }
      } else {
        long gx = row * H3_ + col;
        xr = bf2f(xg[gx]); xz = bf2f(xg[gx + H_]); xn = bf2f(xg[gx + 2 * H_]);
      }
      float r = sig_fast(xr + acc[0][i][rg] + bhr);
      float z = sig_fast(xz + acc[1][i][rg] + bhz);
      float n = tanh_fast(xn + r * (acc[2][i][rg] + bhn));
      long hi = row * H_ + col;
      float hp = bf2f(Aprev[hi]);                 // bf16 h_{t-1} (L2-hot)
      float hv = (1.f - z) * n + z * hp;
      hout[hi] = f2bf(hv);
    }
  }
}

// ---- batched out_seq: one block per b. ew3/a4 arrive pre-scaled by LOG2E2,
// staged as f32 in LDS with conflict-free contiguous-quarter access.
// tanh(x) = 1 - 2*rcp(exp2(x*LOG2E2)+1); "1" folded into svtot=sum(v2).
__global__ __launch_bounds__(256) void out_seq_all(
    const short* __restrict__ ew3,   // (Lenc, B, W) bf16, prescaled
    const short* __restrict__ a4,    // (Ldec, B, W) bf16, prescaled
    const float* __restrict__ v2,
    float* __restrict__ out)
{
  __shared__ float se[L_ * W_];   // 20 KB
  __shared__ float sa[L_ * W_];   // 20 KB
  const int b = blockIdx.x;
  const int tid = threadIdx.x;
  for (int i = tid; i < L_ * 128; i += 256) {
    int row = i >> 7, q = i & 127;
    s4v ev = *(const s4v*)(ew3 + ((long)row * B_ + b) * W_ + q * 4);
    s4v av = *(const s4v*)(a4 + ((long)row * B_ + b) * W_ + q * 4);
    f4v e, a;
#pragma unroll
    for (int j = 0; j < 4; ++j) { e[j] = bf2f(ev[j]); a[j] = bf2f(av[j]); }
    *(f4v*)(se + row * W_ + q * 4) = e;
    *(f4v*)(sa + row * W_ + q * 4) = a;
  }
  const int wave = tid >> 6, lane = tid & 63;
  float sv0[4], sv1[4], svtot = 0.f;
#pragma unroll
  for (int q = 0; q < 4; ++q) {
    float v = v2[lane * 4 + q];
    sv0[q] = -2.f * v; svtot += v;
    v = v2[256 + lane * 4 + q];
    sv1[q] = -2.f * v; svtot += v;
  }
#pragma unroll
  for (int off = 32; off; off >>= 1) svtot += __shfl_down(svtot, off, 64);
  svtot = __shfl(svtot, 0, 64);
  __syncthreads();

  int tprev = -1;
  f4v a0, a1;
#pragma unroll
  for (int pp = 0; pp < 25; ++pp) {
    int p = wave * 25 + pp;       // 100 (t,l) pairs over 4 waves
    int t = p / L_, l = p - t * L_;
    if (t != tprev) {             // wave-uniform branch; a-regs reused
      a0 = *(const f4v*)(sa + t * W_ + lane * 4);
      a1 = *(const f4v*)(sa + t * W_ + 256 + lane * 4);
      tprev = t;
    }
    f4v e0 = *(const f4v*)(se + l * W_ + lane * 4);
    f4v e1 = *(const f4v*)(se + l * W_ + 256 + lane * 4);
    float acc = 0.f;
#pragma unroll
    for (int q = 0; q < 4; ++q) {
      float x0 = __builtin_amdgcn_exp2f(e0[q] + a0[q]);
      acc += sv0[q] * __builtin_amdgcn_rcpf(x0 + 1.f);
      float x1 = __builtin_amdgcn_exp2f(e1[q] + a1[q]);
      acc += sv1[q] * __builtin_amdgcn_rcpf(x1 + 1.f);
    }
#pragma unroll
    for (int off = 32; off; off >>= 1) acc += __shfl_down(acc, off, 64);
    if (lane == 0) out[((long)b * L_ + t) * L_ + l] = svtot + acc;
  }
}

// ---- batched out_ori: one wave per (b,t). ----
__global__ __launch_bounds__(256) void out_ori_all(
    const short* __restrict__ dh,    // (Ldec, B, H) bf16
    const float* __restrict__ wori, const float* __restrict__ bori,
    float* __restrict__ out)
{
  int wid = (blockIdx.x * 256 + threadIdx.x) >> 6;   // b*L + t
  int lane = threadIdx.x & 63;
  int b = wid / L_, t = wid - b * L_;
  s8v hv = *(const s8v*)(dh + ((long)t * B_ + b) * H_ + lane * 8);
  float hf[8];
#pragma unroll
  for (int j = 0; j < 8; ++j) hf[j] = bf2f(hv[j]);
  float res[6];
#pragma unroll
  for (int o = 0; o < 6; ++o) {
    const float* wr = wori + (long)o * H3_ + H_ + lane * 8;
    float acc = 0.f;
#pragma unroll
    for (int j = 0; j < 8; ++j) acc += hf[j] * wr[j];
#pragma unroll
    for (int off = 32; off; off >>= 1) acc += __shfl_down(acc, off, 64);
    res[o] = acc;
  }
  if (lane == 0) {
    float* po = out + ORI_BASE + ((long)b * L_ + t) * 6;
#pragma unroll
    for (int o = 0; o < 6; ++o) po[o] = res[o] + bori[o];
  }
}

extern "C" void kernel_launch(void* const* d_in, const int* in_sizes, int n_in,
                              void* d_out, int out_size, void* d_ws, size_t ws_size,
                              hipStream_t stream)
{
  const float* items   = (const float*)d_in[0];
  const float* dec_in  = (const float*)d_in[1];
  const float* emb_w   = (const float*)d_in[2];
  const float* emb_b   = (const float*)d_in[3];
  const float* enc_wih = (const float*)d_in[4];
  const float* enc_whh = (const float*)d_in[5];
  const float* enc_bih = (const float*)d_in[6];
  const float* enc_bhh = (const float*)d_in[7];
  const float* dec_wih = (const float*)d_in[8];
  const float* dec_whh = (const float*)d_in[9];
  const float* dec_bih = (const float*)d_in[10];
  const float* dec_bhh = (const float*)d_in[11];
  const float* w3      = (const float*)d_in[14];
  const float* w4      = (const float*)d_in[15];
  const float* v2      = (const float*)d_in[20];
  const float* wori    = (const float*)d_in[23];
  const float* bori    = (const float*)d_in[24];
  float* out = (float*)d_out;

  char* ws = (char*)d_ws;
  size_t off = 0;
  auto alloc = [&](size_t bytes) { size_t o = off; off += (bytes + 255) & ~255UL; return o; };
  float* Wc       = (float*)(ws + alloc(H3_ * IN_ * 4));
  float* bc       = (float*)(ws + alloc(H3_ * 4));
  short* xgb      = (short*)(ws + alloc((size_t)B_ * H3_ * 2));          // 12 MiB
  short* enc_hist = (short*)(ws + alloc((size_t)11 * B_ * H_ * 2));      // 44 MiB
  short* dec_hist = (short*)(ws + alloc((size_t)L_ * B_ * H_ * 2));      // 40 MiB
  short* ew3      = (short*)(ws + alloc((size_t)L_ * B_ * W_ * 2));      // 40 MiB
  short* a4       = (short*)(ws + alloc((size_t)L_ * B_ * W_ * 2));      // 40 MiB
  short* whh_e    = (short*)(ws + alloc((size_t)H3_ * H_ * 2));
  short* whh_d    = (short*)(ws + alloc((size_t)H3_ * H_ * 2));
  short* wih_d    = (short*)(ws + alloc((size_t)H3_ * H_ * 2));
  short* w3b      = (short*)(ws + alloc((size_t)W_ * H_ * 2));
  short* w4b      = (short*)(ws + alloc((size_t)W_ * H_ * 2));
  short* decb     = (short*)(ws + alloc((size_t)B_ * H_ * 2));           // 4 MiB

  // ---- prep (one fused conversion dispatch) ----
  prep_all<<<(622592 + 255) / 256, 256, 0, stream>>>(
      enc_whh, whh_e, dec_whh, whh_d, dec_wih, wih_d,
      w3, w3b, w4, w4b, dec_in, decb);
  build_wc<<<384, 256, 0, stream>>>(enc_wih, emb_w, emb_b, enc_bih, Wc, bc);

  hipMemsetAsync(enc_hist, 0, (size_t)B_ * H_ * 2, stream);      // slice 0 = 0

  // xg_dec = dec_in @ dec_wih^T + dec_bih (fixed across decoder steps), bf16
  gemm_bf16<short><<<dim3(12, 32), 256, 0, stream>>>(
      decb, H_, wih_d, H_, dec_bih, xgb, H3_, H_, 1.f);

  // ---- Encoder recurrence: single fused kernel per step (xg inline) ----
  for (int t = 0; t < L_; ++t) {
    gru_fused<true><<<dim3(8, 64), 256, 0, stream>>>(
        enc_hist + (size_t)t * B_ * H_, whh_e, enc_bhh, nullptr,
        items + (size_t)t * IN_, Wc, bc,
        enc_hist + (size_t)(t + 1) * B_ * H_);
  }

  // ---- Decoder recurrence ----
  for (int t = 0; t < L_; ++t) {
    const short* prev = (t == 0) ? enc_hist + (size_t)10 * B_ * H_
                                 : dec_hist + (size_t)(t - 1) * B_ * H_;
    gru_fused<false><<<dim3(8, 64), 256, 0, stream>>>(
        prev, whh_d, dec_bhh, xgb, nullptr, nullptr, nullptr,
        dec_hist + (size_t)t * B_ * H_);
  }

  // ---- Merged batched epilogue (ew3/a4 prescaled by LOG2E2) ----
  gemm_epi<<<dim3(4, 320, 2), 256, 0, stream>>>(
      enc_hist + (size_t)B_ * H_, dec_hist, w3b, w4b, ew3, a4);
  out_seq_all<<<B_, 256, 0, stream>>>(ew3, a4, v2, out);
  out_ori_all<<<(B_ * L_) / 4, 256, 0, stream>>>(dec_hist, wori, bori, out);
}

// Round 8
// 534.113 us; speedup vs baseline: 1.2867x; 1.2265x over previous
//
#include <hip/hip_runtime.h>
#include <hip/hip_bf16.h>

// PointerNetwork: B=4096, L=10, IN=8, H=512, W=512. fp32 in/out, ws=256MiB.
// log_softmax over size-1 axes => hi==he==0. Surviving compute:
//   enc GRU, ew3 = h_enc @ w3^T, dec GRU, a4 = h_dec @ w4^T,
//   out_seq = tanh(ew3+a4)@v2, out_ori = h_dec @ wori[:,H:2H]^T + bori.
// Round 14 = R5's proven gru loop (B staged via global_load_lds -- COALESCED;
// R7's B-in-regs was 64 lanes x 16B at 1KB stride = uncoalesced, -4us/step)
// + validated fp32-h-master removal (blend from bf16 Aprev, absmax unchanged)
// + XCD row-panel swizzle (by=flat&63, bx=flat>>6: all 8 col-blocks of a row
// panel share flat%8 -> same XCD L2; A fetched 1x not 8x per step)
// + merged epilogue GEMM (R7).

#define B_   4096
#define L_   10
#define IN_  8
#define H_   512
#define H3_  1536
#define W_   512
#define ORI_BASE (B_ * L_ * L_)   // 409600

typedef __attribute__((ext_vector_type(8))) short s8v;
typedef __attribute__((ext_vector_type(4))) short s4v;
typedef __attribute__((ext_vector_type(4))) float f4v;

#define LOG2E  1.4426950408889634f
#define LOG2E2 2.8853900817779268f

__device__ __forceinline__ float sig_fast(float x) {
  float e = __builtin_amdgcn_exp2f(-x * LOG2E);
  return __builtin_amdgcn_rcpf(1.f + e);
}
__device__ __forceinline__ float tanh_fast(float x) {
  float e = __builtin_amdgcn_exp2f(x * LOG2E2);
  return 1.f - 2.f * __builtin_amdgcn_rcpf(e + 1.f);
}
__device__ __forceinline__ short f2bf(float f) {
  __hip_bfloat16 h = __float2bfloat16(f);
  return __builtin_bit_cast(short, h);
}
__device__ __forceinline__ float bf2f(short s) {
  __hip_bfloat16 h = __builtin_bit_cast(__hip_bfloat16, s);
  return __bfloat162float(h);
}
__device__ __forceinline__ void stc(float* p, float v) { *p = v; }
__device__ __forceinline__ void stc(short* p, float v) { *p = f2bf(v); }

// ---- fused prep: all fp32->bf16 conversions in one dispatch (6 segments) ----
__global__ __launch_bounds__(256) void prep_all(
    const float* __restrict__ s0, short* __restrict__ d0,   // enc_whh 786432
    const float* __restrict__ s1, short* __restrict__ d1,   // dec_whh 786432
    const float* __restrict__ s2, short* __restrict__ d2,   // dec_wih 786432
    const float* __restrict__ s3, short* __restrict__ d3,   // w3      262144
    const float* __restrict__ s4, short* __restrict__ d4,   // w4      262144
    const float* __restrict__ s5, short* __restrict__ d5)   // dec_in  2097152
{
  long i8 = (long)blockIdx.x * 256 + threadIdx.x;   // unit = 8 elements
  const float* s; short* d; long off;
  if      (i8 < 98304)  { s = s0; d = d0; off = i8; }
  else if (i8 < 196608) { s = s1; d = d1; off = i8 - 98304; }
  else if (i8 < 294912) { s = s2; d = d2; off = i8 - 196608; }
  else if (i8 < 327680) { s = s3; d = d3; off = i8 - 294912; }
  else if (i8 < 360448) { s = s4; d = d4; off = i8 - 327680; }
  else if (i8 < 622592) { s = s5; d = d5; off = i8 - 360448; }
  else return;
  const float* sp = s + off * 8;
  s8v v;
#pragma unroll
  for (int j = 0; j < 8; ++j) v[j] = f2bf(sp[j]);
  *(s8v*)(d + off * 8) = v;
}

// Fold embedding into encoder input weight. One wave per g-row (1536 waves).
__global__ __launch_bounds__(256) void build_wc(
    const float* __restrict__ enc_wih, const float* __restrict__ emb_w,
    const float* __restrict__ emb_b, const float* __restrict__ enc_bih,
    float* __restrict__ Wc, float* __restrict__ bc)
{
  __shared__ float se[H_ * IN_];   // 16 KB
  __shared__ float sb[H_];         // 2 KB
  const int tid = threadIdx.x;
  for (int i = tid; i < H_ * IN_; i += 256) se[i] = emb_w[i];
  for (int i = tid; i < H_; i += 256) sb[i] = emb_b[i];
  __syncthreads();
  int g = (blockIdx.x * 256 + tid) >> 6;
  int lane = tid & 63;
  const float* wr = enc_wih + (long)g * H_ + lane * 8;
  float w8[8];
#pragma unroll
  for (int j = 0; j < 8; ++j) w8[j] = wr[j];
  float acc[9] = {};
#pragma unroll
  for (int kk = 0; kk < 8; ++kk) {
    int k = lane * 8 + kk;
#pragma unroll
    for (int j = 0; j < 8; ++j) acc[j] += w8[kk] * se[k * IN_ + j];
    acc[8] += w8[kk] * sb[k];
  }
#pragma unroll
  for (int j = 0; j < 9; ++j)
#pragma unroll
    for (int off = 32; off; off >>= 1) acc[j] += __shfl_down(acc[j], off, 64);
  if (lane == 0) {
#pragma unroll
    for (int j = 0; j < 8; ++j) Wc[g * IN_ + j] = acc[j];
    bc[g] = acc[8] + enc_bih[g];
  }
}

// ---- Pipelined bf16 MFMA GEMM: C[M,N] = (A@B^T (+bias))*scale.
// 128x128 tile, BK=64, double-buffered LDS (64KB, 2 blk/CU), counted
// vmcnt(8), XOR-swizzled 16B chunks (both-sides), setprio around MFMA.
template <typename CT>
__global__ __launch_bounds__(256) void gemm_bf16(
    const short* __restrict__ A, long lda,
    const short* __restrict__ Bw, long ldb,
    const float* __restrict__ bias,
    CT* __restrict__ C, long ldc, int K, float scale)
{
  __shared__ short As[2][128 * 64];   // 32 KB
  __shared__ short Bs[2][128 * 64];   // 32 KB
  const int tid = threadIdx.x;
  const long row0 = (long)blockIdx.y * 128;
  const long col0 = (long)blockIdx.x * 128;
  const int wave = tid >> 6, lane = tid & 63;
  const int wm = (wave & 1) * 64, wn = (wave >> 1) * 64;
  const int r16 = lane & 15, quad = lane >> 4;
  const int sw = r16 & 7;
  f4v acc[4][4] = {};

  auto stage = [&](int buf, int k0) {
#pragma unroll
    for (int r = 0; r < 4; ++r) {             // A: 128x64 = 1024 chunks
      int idx = r * 256 + tid;
      int m = idx >> 3, c8 = idx & 7;
      int src = c8 ^ (m & 7);
      __builtin_amdgcn_global_load_lds(
          (const __attribute__((address_space(1))) void*)(A + (row0 + m) * lda + k0 + src * 8),
          (__attribute__((address_space(3))) void*)(&As[buf][idx * 8]), 16, 0, 0);
    }
#pragma unroll
    for (int r = 0; r < 4; ++r) {             // B: 128x64 = 1024 chunks
      int idx = r * 256 + tid;
      int m = idx >> 3, c8 = idx & 7;
      int src = c8 ^ (m & 7);
      __builtin_amdgcn_global_load_lds(
          (const __attribute__((address_space(1))) void*)(Bw + (col0 + m) * ldb + k0 + src * 8),
          (__attribute__((address_space(3))) void*)(&Bs[buf][idx * 8]), 16, 0, 0);
    }
  };

  const int nk = K >> 6;
  stage(0, 0);
  for (int k = 0; k < nk; ++k) {
    if (k < nk - 1) {
      stage((k + 1) & 1, (k + 1) * 64);
      asm volatile("s_waitcnt vmcnt(8)" ::: "memory");   // cur's 8 loads done
    } else {
      asm volatile("s_waitcnt vmcnt(0)" ::: "memory");
    }
    __builtin_amdgcn_s_barrier();
    const short* Asc = As[k & 1];
    const short* Bsc = Bs[k & 1];
    s8v af[4][2], bf[4][2];
#pragma unroll
    for (int i = 0; i < 4; ++i)
#pragma unroll
      for (int hh = 0; hh < 2; ++hh)
        af[i][hh] = *(const s8v*)&Asc[(wm + i * 16 + r16) * 64 + ((hh * 4 + quad) ^ sw) * 8];
#pragma unroll
    for (int j = 0; j < 4; ++j)
#pragma unroll
      for (int hh = 0; hh < 2; ++hh)
        bf[j][hh] = *(const s8v*)&Bsc[(wn + j * 16 + r16) * 64 + ((hh * 4 + quad) ^ sw) * 8];
    __builtin_amdgcn_s_setprio(1);
#pragma unroll
    for (int hh = 0; hh < 2; ++hh)
#pragma unroll
      for (int i = 0; i < 4; ++i)
#pragma unroll
        for (int j = 0; j < 4; ++j)
          acc[i][j] = __builtin_amdgcn_mfma_f32_16x16x32_bf16(af[i][hh], bf[j][hh], acc[i][j], 0, 0, 0);
    __builtin_amdgcn_s_setprio(0);
    __builtin_amdgcn_s_barrier();
  }

#pragma unroll
  for (int i = 0; i < 4; ++i) {
    long rbase = row0 + wm + i * 16 + quad * 4;
#pragma unroll
    for (int j = 0; j < 4; ++j) {
      long c = col0 + wn + j * 16 + r16;
      float bv = bias ? bias[c] : 0.f;
#pragma unroll
      for (int rg = 0; rg < 4; ++rg)
        stc(&C[(rbase + rg) * ldc + c], (acc[i][j][rg] + bv) * scale);
    }
  }
}

// ---- Merged epilogue GEMM: z=0 -> ew3 = enc_hist@w3^T; z=1 -> a4 =
// dec_hist@w4^T. Same pipelined body, output *LOG2E2 as bf16.
__global__ __launch_bounds__(256) void gemm_epi(
    const short* __restrict__ Ae, const short* __restrict__ Ad,
    const short* __restrict__ w3b, const short* __restrict__ w4b,
    short* __restrict__ Ce, short* __restrict__ Cd)
{
  const short* A  = blockIdx.z ? Ad : Ae;
  const short* Bw = blockIdx.z ? w4b : w3b;
  short* C        = blockIdx.z ? Cd : Ce;
  __shared__ short As[2][128 * 64];
  __shared__ short Bs[2][128 * 64];
  const int tid = threadIdx.x;
  const long row0 = (long)blockIdx.y * 128;
  const long col0 = (long)blockIdx.x * 128;
  const int wave = tid >> 6, lane = tid & 63;
  const int wm = (wave & 1) * 64, wn = (wave >> 1) * 64;
  const int r16 = lane & 15, quad = lane >> 4;
  const int sw = r16 & 7;
  f4v acc[4][4] = {};

  auto stage = [&](int buf, int k0) {
#pragma unroll
    for (int r = 0; r < 4; ++r) {
      int idx = r * 256 + tid;
      int m = idx >> 3, c8 = idx & 7;
      int src = c8 ^ (m & 7);
      __builtin_amdgcn_global_load_lds(
          (const __attribute__((address_space(1))) void*)(A + (row0 + m) * H_ + k0 + src * 8),
          (__attribute__((address_space(3))) void*)(&As[buf][idx * 8]), 16, 0, 0);
    }
#pragma unroll
    for (int r = 0; r < 4; ++r) {
      int idx = r * 256 + tid;
      int m = idx >> 3, c8 = idx & 7;
      int src = c8 ^ (m & 7);
      __builtin_amdgcn_global_load_lds(
          (const __attribute__((address_space(1))) void*)(Bw + (col0 + m) * H_ + k0 + src * 8),
          (__attribute__((address_space(3))) void*)(&Bs[buf][idx * 8]), 16, 0, 0);
    }
  };

  stage(0, 0);
  for (int k = 0; k < 8; ++k) {
    if (k < 7) {
      stage((k + 1) & 1, (k + 1) * 64);
      asm volatile("s_waitcnt vmcnt(8)" ::: "memory");
    } else {
      asm volatile("s_waitcnt vmcnt(0)" ::: "memory");
    }
    __builtin_amdgcn_s_barrier();
    const short* Asc = As[k & 1];
    const short* Bsc = Bs[k & 1];
    s8v af[4][2], bf[4][2];
#pragma unroll
    for (int i = 0; i < 4; ++i)
#pragma unroll
      for (int hh = 0; hh < 2; ++hh)
        af[i][hh] = *(const s8v*)&Asc[(wm + i * 16 + r16) * 64 + ((hh * 4 + quad) ^ sw) * 8];
#pragma unroll
    for (int j = 0; j < 4; ++j)
#pragma unroll
      for (int hh = 0; hh < 2; ++hh)
        bf[j][hh] = *(const s8v*)&Bsc[(wn + j * 16 + r16) * 64 + ((hh * 4 + quad) ^ sw) * 8];
    __builtin_amdgcn_s_setprio(1);
#pragma unroll
    for (int hh = 0; hh < 2; ++hh)
#pragma unroll
      for (int i = 0; i < 4; ++i)
#pragma unroll
        for (int j = 0; j < 4; ++j)
          acc[i][j] = __builtin_amdgcn_mfma_f32_16x16x32_bf16(af[i][hh], bf[j][hh], acc[i][j], 0, 0, 0);
    __builtin_amdgcn_s_setprio(0);
    __builtin_amdgcn_s_barrier();
  }

#pragma unroll
  for (int i = 0; i < 4; ++i) {
    long rbase = row0 + wm + i * 16 + quad * 4;
#pragma unroll
    for (int j = 0; j < 4; ++j) {
      long c = col0 + wn + j * 16 + r16;
#pragma unroll
      for (int rg = 0; rg < 4; ++rg)
        C[(rbase + rg) * W_ + c] = f2bf(acc[i][j][rg] * LOG2E2);
    }
  }
}

// ---- Fused GRU step (R5 loop + XCD row-panel swizzle + no fp32 h master).
// Tile: 64 rows x 64 cols x 3 gates. Flat grid 512, 256 thr (4 waves,
// 2 blk/CU). by = flat&63, bx = flat>>6 -> the 8 col-blocks of a row panel
// share flat%8 (= by%8) -> same XCD L2; A panel fetched once per step.
// BK=64, dbuf LDS (64KB), counted vmcnt(8), XOR-swizzle, setprio.
template <bool ENC>
__global__ __launch_bounds__(256) void gru_fused(
    const short* __restrict__ Aprev,  // (B,H) bf16 h_{t-1}
    const short* __restrict__ Whh,    // (3H,H) bf16
    const float* __restrict__ bhh,    // (3H)
    const short* __restrict__ xg,     // (B,3H) bf16 (decoder)
    const float* __restrict__ items_t,// encoder: &items[0][t][0], row stride 80
    const float* __restrict__ Wc,     // (3H,8)
    const float* __restrict__ bc,     // (3H)
    short* __restrict__ hout)         // (B,H) bf16 history slice
{
  __shared__ short As[2][64 * 64];    // 16 KB
  __shared__ short Bs[2][192 * 64];   // 48 KB
  const int tid = threadIdx.x;
  const int flat = blockIdx.x;
  const int by = flat & 63, bx = flat >> 6;   // XCD row-panel swizzle
  const long row0 = (long)by * 64;
  const int col0 = bx * 64;
  const int wave = tid >> 6, lane = tid & 63;
  const int r16 = lane & 15, quad = lane >> 4;
  const int sw = r16 & 7;

  f4v acc[3][4] = {};   // [gate][frag-row]

  auto stage = [&](int buf, int k0) {
#pragma unroll
    for (int r = 0; r < 2; ++r) {             // A: 64x64 = 512 chunks
      int idx = r * 256 + tid;
      int m = idx >> 3, c8 = idx & 7;
      int src = c8 ^ (m & 7);
      __builtin_amdgcn_global_load_lds(
          (const __attribute__((address_space(1))) void*)(Aprev + (row0 + m) * H_ + k0 + src * 8),
          (__attribute__((address_space(3))) void*)(&As[buf][idx * 8]), 16, 0, 0);
    }
#pragma unroll
    for (int r = 0; r < 6; ++r) {             // B: 192x64 = 1536 chunks
      int idx = r * 256 + tid;
      int m = idx >> 3, c8 = idx & 7;
      int src = c8 ^ (m & 7);
      int g = m >> 6, cc = m & 63;
      __builtin_amdgcn_global_load_lds(
          (const __attribute__((address_space(1))) void*)(Whh + ((long)g * H_ + col0 + cc) * H_ + k0 + src * 8),
          (__attribute__((address_space(3))) void*)(&Bs[buf][idx * 8]), 16, 0, 0);
    }
  };

  stage(0, 0);
  int cur = 0;
  for (int k = 0; k < 8; ++k) {
    if (k < 7) {
      stage(cur ^ 1, (k + 1) * 64);
      asm volatile("s_waitcnt vmcnt(8)" ::: "memory");   // cur's 8 loads done
    } else {
      asm volatile("s_waitcnt vmcnt(0)" ::: "memory");
    }
    __builtin_amdgcn_s_barrier();
    s8v af[4][2], bf[3][2];
#pragma unroll
    for (int i = 0; i < 4; ++i)
#pragma unroll
      for (int hh = 0; hh < 2; ++hh)
        af[i][hh] = *(const s8v*)&As[cur][(i * 16 + r16) * 64 + ((hh * 4 + quad) ^ sw) * 8];
#pragma unroll
    for (int g = 0; g < 3; ++g)
#pragma unroll
      for (int hh = 0; hh < 2; ++hh)
        bf[g][hh] = *(const s8v*)&Bs[cur][(g * 64 + wave * 16 + r16) * 64 + ((hh * 4 + quad) ^ sw) * 8];
    __builtin_amdgcn_s_setprio(1);
#pragma unroll
    for (int hh = 0; hh < 2; ++hh)
#pragma unroll
      for (int g = 0; g < 3; ++g)
#pragma unroll
        for (int i = 0; i < 4; ++i)
          acc[g][i] = __builtin_amdgcn_mfma_f32_16x16x32_bf16(af[i][hh], bf[g][hh], acc[g][i], 0, 0, 0);
    __builtin_amdgcn_s_setprio(0);
    __builtin_amdgcn_s_barrier();
    cur ^= 1;
  }

  // Column owned by this thread (C/D layout: col=lane&15, row=quad*4+reg).
  const int col = col0 + wave * 16 + r16;
  float wc[3][8], bcv[3];
  if (ENC) {
#pragma unroll
    for (int g = 0; g < 3; ++g) {
      const float* wr = Wc + ((long)g * H_ + col) * IN_;
#pragma unroll
      for (int j = 0; j < 8; ++j) wc[g][j] = wr[j];
      bcv[g] = bc[g * H_ + col];
    }
    // stage items rows into LDS (reuse As): 64 rows x 8 fp32
    float* itemS = (float*)As;
    int i2 = tid * 2;
    int m = i2 >> 3, j = i2 & 7;
    itemS[i2] = items_t[(row0 + m) * (L_ * IN_) + j];
    itemS[i2 + 1] = items_t[(row0 + m) * (L_ * IN_) + j + 1];
    __syncthreads();
  }
  float bhr = bhh[col], bhz = bhh[col + H_], bhn = bhh[col + 2 * H_];

#pragma unroll
  for (int i = 0; i < 4; ++i) {
#pragma unroll
    for (int rg = 0; rg < 4; ++rg) {
      int rl = i * 16 + quad * 4 + rg;
      long row = row0 + rl;
      float xr, xz, xn;
      if (ENC) {
        const float* it = (const float*)As + rl * 8;
        xr = bcv[0]; xz = bcv[1]; xn = bcv[2];
#pragma unroll
        for (int j = 0; j < 8; ++j) {
          float iv = it[j];
          xr += iv * wc[0][j];
          xz += iv * wc[1][j];
          xn += iv * wc[2][j];
        }
      } else {
        long gx = row * H3_ + col;
        xr = bf2f(xg[gx]); xz = bf2f(xg[gx + H_]); xn = bf2f(xg[gx + 2 * H_]);
      }
      float r = sig_fast(xr + acc[0][i][rg] + bhr);
      float z = sig_fast(xz + acc[1][i][rg] + bhz);
      float n = tanh_fast(xn + r * (acc[2][i][rg] + bhn));
      long hi = row * H_ + col;
      float hp = bf2f(Aprev[hi]);                 // bf16 h_{t-1} (L2-hot)
      float hv = (1.f - z) * n + z * hp;
      hout[hi] = f2bf(hv);
    }
  }
}

// ---- batched out_seq: one block per b. ew3/a4 arrive pre-scaled by LOG2E2,
// staged as f32 in LDS with conflict-free contiguous-quarter access.
// tanh(x) = 1 - 2*rcp(exp2(x*LOG2E2)+1); "1" folded into svtot=sum(v2).
__global__ __launch_bounds__(256) void out_seq_all(
    const short* __restrict__ ew3,   // (Lenc, B, W) bf16, prescaled
    const short* __restrict__ a4,    // (Ldec, B, W) bf16, prescaled
    const float* __restrict__ v2,
    float* __restrict__ out)
{
  __shared__ float se[L_ * W_];   // 20 KB
  __shared__ float sa[L_ * W_];   // 20 KB
  const int b = blockIdx.x;
  const int tid = threadIdx.x;
  for (int i = tid; i < L_ * 128; i += 256) {
    int row = i >> 7, q = i & 127;
    s4v ev = *(const s4v*)(ew3 + ((long)row * B_ + b) * W_ + q * 4);
    s4v av = *(const s4v*)(a4 + ((long)row * B_ + b) * W_ + q * 4);
    f4v e, a;
#pragma unroll
    for (int j = 0; j < 4; ++j) { e[j] = bf2f(ev[j]); a[j] = bf2f(av[j]); }
    *(f4v*)(se + row * W_ + q * 4) = e;
    *(f4v*)(sa + row * W_ + q * 4) = a;
  }
  const int wave = tid >> 6, lane = tid & 63;
  float sv0[4], sv1[4], svtot = 0.f;
#pragma unroll
  for (int q = 0; q < 4; ++q) {
    float v = v2[lane * 4 + q];
    sv0[q] = -2.f * v; svtot += v;
    v = v2[256 + lane * 4 + q];
    sv1[q] = -2.f * v; svtot += v;
  }
#pragma unroll
  for (int off = 32; off; off >>= 1) svtot += __shfl_down(svtot, off, 64);
  svtot = __shfl(svtot, 0, 64);
  __syncthreads();

  int tprev = -1;
  f4v a0, a1;
#pragma unroll
  for (int pp = 0; pp < 25; ++pp) {
    int p = wave * 25 + pp;       // 100 (t,l) pairs over 4 waves
    int t = p / L_, l = p - t * L_;
    if (t != tprev) {             // wave-uniform branch; a-regs reused
      a0 = *(const f4v*)(sa + t * W_ + lane * 4);
      a1 = *(const f4v*)(sa + t * W_ + 256 + lane * 4);
      tprev = t;
    }
    f4v e0 = *(const f4v*)(se + l * W_ + lane * 4);
    f4v e1 = *(const f4v*)(se + l * W_ + 256 + lane * 4);
    float acc = 0.f;
#pragma unroll
    for (int q = 0; q < 4; ++q) {
      float x0 = __builtin_amdgcn_exp2f(e0[q] + a0[q]);
      acc += sv0[q] * __builtin_amdgcn_rcpf(x0 + 1.f);
      float x1 = __builtin_amdgcn_exp2f(e1[q] + a1[q]);
      acc += sv1[q] * __builtin_amdgcn_rcpf(x1 + 1.f);
    }
#pragma unroll
    for (int off = 32; off; off >>= 1) acc += __shfl_down(acc, off, 64);
    if (lane == 0) out[((long)b * L_ + t) * L_ + l] = svtot + acc;
  }
}

// ---- batched out_ori: one wave per (b,t). ----
__global__ __launch_bounds__(256) void out_ori_all(
    const short* __restrict__ dh,    // (Ldec, B, H) bf16
    const float* __restrict__ wori, const float* __restrict__ bori,
    float* __restrict__ out)
{
  int wid = (blockIdx.x * 256 + threadIdx.x) >> 6;   // b*L + t
  int lane = threadIdx.x & 63;
  int b = wid / L_, t = wid - b * L_;
  s8v hv = *(const s8v*)(dh + ((long)t * B_ + b) * H_ + lane * 8);
  float hf[8];
#pragma unroll
  for (int j = 0; j < 8; ++j) hf[j] = bf2f(hv[j]);
  float res[6];
#pragma unroll
  for (int o = 0; o < 6; ++o) {
    const float* wr = wori + (long)o * H3_ + H_ + lane * 8;
    float acc = 0.f;
#pragma unroll
    for (int j = 0; j < 8; ++j) acc += hf[j] * wr[j];
#pragma unroll
    for (int off = 32; off; off >>= 1) acc += __shfl_down(acc, off, 64);
    res[o] = acc;
  }
  if (lane == 0) {
    float* po = out + ORI_BASE + ((long)b * L_ + t) * 6;
#pragma unroll
    for (int o = 0; o < 6; ++o) po[o] = res[o] + bori[o];
  }
}

extern "C" void kernel_launch(void* const* d_in, const int* in_sizes, int n_in,
                              void* d_out, int out_size, void* d_ws, size_t ws_size,
                              hipStream_t stream)
{
  const float* items   = (const float*)d_in[0];
  const float* dec_in  = (const float*)d_in[1];
  const float* emb_w   = (const float*)d_in[2];
  const float* emb_b   = (const float*)d_in[3];
  const float* enc_wih = (const float*)d_in[4];
  const float* enc_whh = (const float*)d_in[5];
  const float* enc_bih = (const float*)d_in[6];
  const float* enc_bhh = (const float*)d_in[7];
  const float* dec_wih = (const float*)d_in[8];
  const float* dec_whh = (const float*)d_in[9];
  const float* dec_bih = (const float*)d_in[10];
  const float* dec_bhh = (const float*)d_in[11];
  const float* w3      = (const float*)d_in[14];
  const float* w4      = (const float*)d_in[15];
  const float* v2      = (const float*)d_in[20];
  const float* wori    = (const float*)d_in[23];
  const float* bori    = (const float*)d_in[24];
  float* out = (float*)d_out;

  char* ws = (char*)d_ws;
  size_t off = 0;
  auto alloc = [&](size_t bytes) { size_t o = off; off += (bytes + 255) & ~255UL; return o; };
  float* Wc       = (float*)(ws + alloc(H3_ * IN_ * 4));
  float* bc       = (float*)(ws + alloc(H3_ * 4));
  short* xgb      = (short*)(ws + alloc((size_t)B_ * H3_ * 2));          // 12 MiB
  short* enc_hist = (short*)(ws + alloc((size_t)11 * B_ * H_ * 2));      // 44 MiB
  short* dec_hist = (short*)(ws + alloc((size_t)L_ * B_ * H_ * 2));      // 40 MiB
  short* ew3      = (short*)(ws + alloc((size_t)L_ * B_ * W_ * 2));      // 40 MiB
  short* a4       = (short*)(ws + alloc((size_t)L_ * B_ * W_ * 2));      // 40 MiB
  short* whh_e    = (short*)(ws + alloc((size_t)H3_ * H_ * 2));
  short* whh_d    = (short*)(ws + alloc((size_t)H3_ * H_ * 2));
  short* wih_d    = (short*)(ws + alloc((size_t)H3_ * H_ * 2));
  short* w3b      = (short*)(ws + alloc((size_t)W_ * H_ * 2));
  short* w4b      = (short*)(ws + alloc((size_t)W_ * H_ * 2));
  short* decb     = (short*)(ws + alloc((size_t)B_ * H_ * 2));           // 4 MiB

  // ---- prep (one fused conversion dispatch) ----
  prep_all<<<(622592 + 255) / 256, 256, 0, stream>>>(
      enc_whh, whh_e, dec_whh, whh_d, dec_wih, wih_d,
      w3, w3b, w4, w4b, dec_in, decb);
  build_wc<<<384, 256, 0, stream>>>(enc_wih, emb_w, emb_b, enc_bih, Wc, bc);

  hipMemsetAsync(enc_hist, 0, (size_t)B_ * H_ * 2, stream);      // slice 0 = 0

  // xg_dec = dec_in @ dec_wih^T + dec_bih (fixed across decoder steps), bf16
  gemm_bf16<short><<<dim3(12, 32), 256, 0, stream>>>(
      decb, H_, wih_d, H_, dec_bih, xgb, H3_, H_, 1.f);

  // ---- Encoder recurrence: single fused kernel per step (xg inline) ----
  for (int t = 0; t < L_; ++t) {
    gru_fused<true><<<512, 256, 0, stream>>>(
        enc_hist + (size_t)t * B_ * H_, whh_e, enc_bhh, nullptr,
        items + (size_t)t * IN_, Wc, bc,
        enc_hist + (size_t)(t + 1) * B_ * H_);
  }

  // ---- Decoder recurrence ----
  for (int t = 0; t < L_; ++t) {
    const short* prev = (t == 0) ? enc_hist + (size_t)10 * B_ * H_
                                 : dec_hist + (size_t)(t - 1) * B_ * H_;
    gru_fused<false><<<512, 256, 0, stream>>>(
        prev, whh_d, dec_bhh, xgb, nullptr, nullptr, nullptr,
        dec_hist + (size_t)t * B_ * H_);
  }

  // ---- Merged batched epilogue (ew3/a4 prescaled by LOG2E2) ----
  gemm_epi<<<dim3(4, 320, 2), 256, 0, stream>>>(
      enc_hist + (size_t)B_ * H_, dec_hist, w3b, w4b, ew3, a4);
  out_seq_all<<<B_, 256, 0, stream>>>(ew3, a4, v2, out);
  out_ori_all<<<(B_ * L_) / 4, 256, 0, stream>>>(dec_hist, wori, bori, out);
}